// Round 11
// baseline (150.828 us; speedup 1.0000x reference)
//
#include <hip/hip_runtime.h>
#if __has_include(<hip/hip_fp8.h>)
#include <hip/hip_fp8.h>
#endif

// ---------------------------------------------------------------------------
// MHABlock: cvt (+l_tot zero, sqrt-softmax-scale folded into Wq AND Wk) ->
// QKV GEMM (bf16, 64x128 tiles, BK=128, global_load_lds, XCD-pinned m-tiles;
// Q-mode writes fp8 directly) -> fused K/V transpose + fp8 convert (+vals
// zero; rows PERMUTED at 8B level for conflict-free b128 attn reads) ->
// split-K(3) fp8 flash attention (R20 structure) -> deferred norm + LN.
//
// R25: gemm residency fix. 480 blocks = 1.875/CU ~ 7.5 waves/CU: most CUs
// hold ONE gemm block, so every K-step vmcnt(0)+barrier drain idles the
// whole CU (m114 overlap needs >=2-3 resident blocks; m97's 900TF ran ~3/CU;
// our est. gemm eff ~300TF). M-tile 128->64: grid 960 = 3.75/CU, LDS 48KB ->
// 3 blocks/CU, 15 waves/CU (2x). Same staging/swizzle formulas; XCD pinning
// preserved (b%8 == g%8, A-tile's 15 consumers share one L2). B re-reads
// double (+75MB L2 ~ 2us) -- cheap vs the residency win. BK=128 kept (R24:
// +2.1us).
// ---------------------------------------------------------------------------

typedef __bf16 bf16x8 __attribute__((ext_vector_type(8)));
typedef __bf16 bf16x4 __attribute__((ext_vector_type(4)));
typedef float  f32x4  __attribute__((ext_vector_type(4)));
typedef unsigned short u16x4 __attribute__((ext_vector_type(4)));
typedef unsigned int   u32x4 __attribute__((ext_vector_type(4)));
typedef long           lx2   __attribute__((ext_vector_type(2)));
typedef lx2            lx2a  __attribute__((may_alias));
typedef long           la64  __attribute__((may_alias));
typedef unsigned int   ua32  __attribute__((may_alias));

#define N_TOK   4096
#define D_MODEL 640
#define DK      64
#define HSLAB   (N_TOK * DK)
// sqrt(log2(e)/64): folded into BOTH Wq and Wk -> logits arrive base-2 scaled
#define SQS 0.15014030f

#if __has_builtin(__builtin_amdgcn_exp2f)
#define EXP2(x) __builtin_amdgcn_exp2f(x)
#else
#define EXP2(x) exp2f(x)
#endif

__device__ __forceinline__ void stage16(const void* g, void* lds_uniform) {
    __builtin_amdgcn_global_load_lds(
        (const __attribute__((address_space(1))) unsigned int*)g,
        (__attribute__((address_space(3))) unsigned int*)lds_uniform, 16, 0, 0);
}

__device__ __forceinline__ u16x4 cvt4(f32x4 v) {
    return __builtin_bit_cast(u16x4, __builtin_convertvector(v, bf16x4));
}

__device__ __forceinline__ unsigned int pk_fp8(f32x4 v) {
#if __has_builtin(__builtin_amdgcn_cvt_pk_fp8_f32)
    int r = 0;
    r = __builtin_amdgcn_cvt_pk_fp8_f32(v[0], v[1], r, false);
    r = __builtin_amdgcn_cvt_pk_fp8_f32(v[2], v[3], r, true);
    return (unsigned int)r;
#else
    union { unsigned char b[4]; unsigned int u; } x;
    x.b[0] = __hip_fp8_e4m3(v[0]).__x;
    x.b[1] = __hip_fp8_e4m3(v[1]).__x;
    x.b[2] = __hip_fp8_e4m3(v[2]).__x;
    x.b[3] = __hip_fp8_e4m3(v[3]).__x;
    return x.u;
#endif
}

// ---------- fused fp32 -> bf16 (x, Wq*s, Wk*s, Wv) + l_tot zeroing ---------
__global__ __launch_bounds__(256) void cvt_all(const float* __restrict__ x,
                                               const float* __restrict__ w0,
                                               const float* __restrict__ w1,
                                               const float* __restrict__ w2,
                                               unsigned short* __restrict__ xb,
                                               unsigned short* __restrict__ d0,
                                               unsigned short* __restrict__ d1,
                                               unsigned short* __restrict__ d2,
                                               f32x4* __restrict__ ltot4) {
    int i = blockIdx.x * 256 + threadIdx.x;
    if (i >= 962560) { ltot4[i - 962560] = (f32x4){0.f, 0.f, 0.f, 0.f}; return; }
    const float* s; unsigned short* d; int off; float scl = 1.0f;
    if (i < 655360) { s = x; d = xb; off = i; }
    else {
        int j = i - 655360;
        int w = j / 102400; off = j - w * 102400;
        s = (w == 0) ? w0 : (w == 1) ? w1 : w2;
        d = (w == 0) ? d0 : (w == 1) ? d1 : d2;
        if (w < 2) scl = SQS;   // Wq, Wk carry sqrt of softmax scale
    }
    f32x4 v = ((const f32x4*)s)[off];
    v[0] *= scl; v[1] *= scl; v[2] *= scl; v[3] *= scl;
    ((u16x4*)d)[off] = cvt4(v);
}

// ------------------------ QKV NT-GEMM: C = x @ W^T -------------------------
// M=4096, N=640, K=640. 64x128 tile, BK=128 (5 K-steps), 4 waves each 32x64.
// Grid 960 linear: b = r*64 + g; g = b&63 = m-tile (XCD-pinned: b%8==g%8),
// r = 0..14 = (mode, n-tile). mode 0 (Q): epilogue converts straight to fp8.
__global__ __launch_bounds__(256, 3) void gemm_qkv(
    const unsigned short* __restrict__ xb,
    const unsigned short* __restrict__ wq,
    const unsigned short* __restrict__ wk,
    const unsigned short* __restrict__ wv,
    unsigned char*  __restrict__ Qf8o,
    unsigned short* __restrict__ Ko,
    unsigned short* __restrict__ Vo) {
    const int b = blockIdx.x;
    const int g = b & 63;            // m-tile (XCD-pinned)
    const int r = b >> 6;            // 0..14 = (mode, n-tile)
    const int mode = r / 5;
    const int m0 = g * 64;
    const int n0 = (r % 5) * 128;
    const unsigned short* W = (mode == 0) ? wq : (mode == 1) ? wk : wv;
    unsigned short*       C = (mode == 1) ? Ko : Vo;

    __shared__ unsigned short As[8192];    // 64 rows x 128
    __shared__ unsigned short Bs[16384];   // 128 rows x 128

    const int tid  = threadIdx.x;
    const int lane = tid & 63;
    const int wave = tid >> 6;
    const int quad = lane >> 4, l16 = lane & 15;
    const int wm = (wave >> 1) * 32, wn = (wave & 1) * 64;
    const int swz = l16 & 7;

    f32x4 acc[2][4] = {};

    // chunk p = j*256+tid: row = p>>4 (16 chunks of 8 bf16 per 128-col row),
    // source col-chunk = (p&15)^(row&7) (low-3-bit XOR, bijective per row).
    // A uses j=0..3 (1024 chunks), B uses j=0..7 (2048 chunks).
    int prow[8], pcol[8], lbase[8];
    for (int j = 0; j < 8; j++) {
        int p = j * 256 + tid;
        prow[j] = p >> 4;
        pcol[j] = ((p & 15) ^ (prow[j] & 7)) * 8;
        lbase[j] = (j * 256 + wave * 64) * 8;
    }

    for (int kt = 0; kt < D_MODEL; kt += 128) {
        __syncthreads();
        for (int j = 0; j < 4; j++)
            stage16(&xb[(size_t)(m0 + prow[j]) * D_MODEL + kt + pcol[j]], As + lbase[j]);
        for (int j = 0; j < 8; j++)
            stage16(&W [(size_t)(n0 + prow[j]) * D_MODEL + kt + pcol[j]], Bs + lbase[j]);
        __syncthreads();

        for (int s = 0; s < 4; s++) {
            bf16x8 af[2], bfr[4];
            for (int mi = 0; mi < 2; mi++) {
                int row = wm + mi * 16 + l16;
                af[mi] = *(const bf16x8*)&As[row * 128 + ((((s << 2) + quad) ^ swz) * 8)];
            }
            for (int ni = 0; ni < 4; ni++) {
                int row = wn + ni * 16 + l16;
                bfr[ni] = *(const bf16x8*)&Bs[row * 128 + ((((s << 2) + quad) ^ swz) * 8)];
            }
            for (int mi = 0; mi < 2; mi++)
                for (int ni = 0; ni < 4; ni++)
                    acc[mi][ni] = __builtin_amdgcn_mfma_f32_16x16x32_bf16(af[mi], bfr[ni], acc[mi][ni], 0, 0, 0);
        }
    }

    if (mode == 0) {
        for (int mi = 0; mi < 2; mi++)
            for (int ni = 0; ni < 4; ni++) {
                unsigned int p = pk_fp8(acc[mi][ni]);
                for (int r2 = 0; r2 < 4; r2++) {
                    int row = m0 + wm + mi * 16 + quad * 4 + r2;
                    int col = n0 + wn + ni * 16 + l16;
                    Qf8o[(size_t)row * D_MODEL + col] = (unsigned char)(p >> (r2 * 8));
                }
            }
    } else {
        for (int mi = 0; mi < 2; mi++)
            for (int ni = 0; ni < 4; ni++) {
                u16x4 cv = cvt4(acc[mi][ni]);
                for (int r2 = 0; r2 < 4; r2++) {
                    int row = m0 + wm + mi * 16 + quad * 4 + r2;
                    int col = n0 + wn + ni * 16 + l16;
                    C[(size_t)row * D_MODEL + col] = cv[r2];
                }
            }
    }
}

// ------ fused per-head transpose -> fp8 (K',V') + vals zero ----------------
// R20: dst bytes within each 64B group are PERMUTED: original in-group byte
// p lands at p' = ((p&31)>>3)*16 + (p>>5)*8 + (p&7) -> single ds_read_b128
// per operand pair in attn, even bank spread.
__global__ __launch_bounds__(256) void transpose_kv(
    const unsigned short* __restrict__ Kn, unsigned char* __restrict__ Kp8,
    const unsigned short* __restrict__ Vn, unsigned char* __restrict__ Vp8) {
    const int z = blockIdx.z;
    const int t = threadIdx.x;

    __shared__ unsigned short T[64][66];
    const unsigned short* src; unsigned char* dst;
    int R, Cc, r0, c0;
    if (z < 10) { src = Kn; dst = Kp8; R = 64;   Cc = 4096; r0 = 0; c0 = blockIdx.x * 64; }
    else        { src = Vn; dst = Vp8; R = 4096; Cc = 64;   r0 = blockIdx.x * 64; c0 = 0; }
    const size_t hb = (size_t)(z % 10) * HSLAB;
    const int rr = t >> 3, c8 = (t & 7) * 8;
    const int pbase = ((c8 & 31) >> 3) * 16 + (c8 >> 5) * 8;   // 8B-block permute

    for (int hf = 0; hf < 2; hf++) {
        int r = rr + hf * 32;
        bf16x8 v = *(const bf16x8*)&src[hb + (size_t)(r0 + r) * Cc + c0 + c8];
        for (int j = 0; j < 8; j++) T[r][c8 + j] = ((unsigned short*)&v)[j];
    }
    __syncthreads();
    // zero the consumed source tile (Kn+Vn exactly cover the fp32 vals buf)
    const bf16x8 zz = {};
    for (int hf = 0; hf < 2; hf++) {
        int r = rr + hf * 32;
        *(bf16x8*)&((unsigned short*)src)[hb + (size_t)(r0 + r) * Cc + c0 + c8] = zz;
    }
    for (int hf = 0; hf < 2; hf++) {
        int oc = rr + hf * 32;
        f32x4 lo, hi;
        for (int j = 0; j < 4; j++) {
            lo[j] = __builtin_bit_cast(float, (unsigned int)T[c8 + j][oc] << 16);
            hi[j] = __builtin_bit_cast(float, (unsigned int)T[c8 + 4 + j][oc] << 16);
        }
        uint2 ov; ov.x = pk_fp8(lo); ov.y = pk_fp8(hi);
        size_t dcol = (z < 10) ? ((size_t)(c0 + oc) * 64 + pbase)
                               : ((size_t)oc * 4096 + r0 + pbase);
        *(uint2*)&dst[hb + dcol] = ov;
    }
}

// ------------------------------- attention (fp8) ---------------------------
// grid (320, 3): x = head*32 + qtile(128 rows), y = kpart (11/11/10 tiles of
// 128 keys). 4 waves x 32 q. 2 barriers/tile, ping-pong K, V under S
// (R14 schedule; R20 conflict-free K/V LDS addressing; 52.5us measured).
__global__ __launch_bounds__(256, 4) void attn(
    const unsigned char* __restrict__ Qf8,   // [h][q][dk] fp8
    const unsigned char* __restrict__ Kp8,   // [h][key][dk-permuted] fp8
    const unsigned char* __restrict__ Vp8,   // [h][dk][key-permuted] fp8
    float* __restrict__ vals,                // pre-zeroed (transpose_kv)
    float* __restrict__ l_tot) {             // pre-zeroed (cvt_all)
    const int h  = blockIdx.x >> 5;
    const int qt = blockIdx.x & 31;
    const int ntile = (blockIdx.y == 2) ? 10 : 11;
    const int tile0 = blockIdx.y * 11;
    const int lane = threadIdx.x & 63;
    const int wave = threadIdx.x >> 6;
    const int quad = lane >> 4, l16 = lane & 15;
    const size_t hoff = (size_t)h * HSLAB;

    __shared__ unsigned char sm[40960];
    unsigned char* const Kb0 = sm;                      // 8KB, ping
    unsigned char* const Kb1 = sm + 8192;               // 8KB, pong
    unsigned char* const Vt  = sm + 16384;              // 8KB
    unsigned char* const Pw  = sm + 24576 + wave * 4096;// 4KB/wave

    const int qbase = qt * 128 + wave * 32;
    long qd[2][2];
    for (int g = 0; g < 2; g++) {
        const unsigned char* qp = Qf8 + hoff + (size_t)(qbase + g * 16 + l16) * 64 + quad * 8;
        qd[g][0] = *(const la64*)(qp);
        qd[g][1] = *(const la64*)(qp + 32);
    }

    f32x4 o[2][4] = {};
    f32x4 ol[2] = {};
    const long ONES8 = 0x3838383838383838L;   // e4m3 1.0 x8

    // staging chunks (16B each, 2 per thread per buffer): LDS dest linear
    // (chunk c at byte c*16). K source linear; V source inverse-swizzled.
    const int cA = wave * 64 + lane, cB = cA + 256;
    const int vDA = cA >> 3, vSA = ((cA & 7) * 16) ^ ((vDA & 7) << 4);
    const int vDB = cB >> 3, vSB = ((cB & 7) * 16) ^ ((vDB & 7) << 4);

    // fragment-read bases
    const int kfb = l16 * 64 + quad * 16;     // + ni*1024, b128
    const int vrb = l16 * 128;                // + nd*2048, b128
    const int vx  = (l16 & 7) << 4;           // V row XOR

    // prologue: stage K tile 0 into Kb0
    {
        const size_t kb0 = hoff + (size_t)(tile0 << 7) * 64;
        stage16(Kp8 + kb0 + cA * 16, Kb0 + wave * 1024);
        stage16(Kp8 + kb0 + cB * 16, Kb0 + 4096 + wave * 1024);
    }

    for (int t = 0; t < ntile; t++) {
        const int keyb = (tile0 + t) << 7;
        unsigned char* const Kcur = (t & 1) ? Kb1 : Kb0;

        // K[t] drained by previous mid barrier (or here for t=0); Vt/Pw reads
        // of t-1 complete; K[t+1] buffer free.
        __syncthreads();

        if (t + 1 < ntile) {
            const size_t kbn = hoff + (size_t)((tile0 + t + 1) << 7) * 64;
            unsigned char* const Knext = (t & 1) ? Kb0 : Kb1;
            stage16(Kp8 + kbn + cA * 16, Knext + wave * 1024);
            stage16(Kp8 + kbn + cB * 16, Knext + 4096 + wave * 1024);
        }
        stage16(Vp8 + hoff + (size_t)vDA * N_TOK + keyb + vSA, Vt + wave * 1024);
        stage16(Vp8 + hoff + (size_t)vDB * N_TOK + keyb + vSB, Vt + 4096 + wave * 1024);

        // ---- S^T: A = K rows (key), B = Q (pre-scaled); exp2 -> P fp8 ----
        for (int ni = 0; ni < 8; ni++) {
            lx2 kk = *(const lx2a*)(Kcur + ni * 1024 + kfb);
            for (int g = 0; g < 2; g++) {
                f32x4 s = {};
                s = __builtin_amdgcn_mfma_f32_16x16x32_fp8_fp8(kk[0], qd[g][0], s, 0, 0, 0);
                s = __builtin_amdgcn_mfma_f32_16x16x32_fp8_fp8(kk[1], qd[g][1], s, 0, 0, 0);
                f32x4 pv;
                for (int r = 0; r < 4; r++) pv[r] = EXP2(s[r]);
                const int pu = ni * 2 + (quad >> 1);
                *(ua32*)(Pw + pu * 256 +
                         (((g * 16 + l16) + ((pu & 3) << 3)) & 31) * 8 +
                         (quad & 1) * 4) = pk_fp8(pv);
            }
        }

        // Drains vmcnt (V[t] + K[t+1] staged) and lgkmcnt (P visible).
        __syncthreads();

        // ---- O += P * V, l += P * 1 ----
        for (int ksp = 0; ksp < 2; ksp++) {
            lx2 vv[4];
            for (int nd = 0; nd < 4; nd++)
                vv[nd] = *(const lx2a*)(Vt + nd * 2048 + vrb +
                                        ((ksp * 64 + quad * 16) ^ vx));
            for (int kh = 0; kh < 2; kh++) {
                const int ks = ksp * 2 + kh;
                for (int g = 0; g < 2; g++) {
                    // reader pu = ks*4+quad -> pu&3 == quad
                    long pf = *(const la64*)(Pw + (ks * 4 + quad) * 256 +
                                             (((g * 16 + l16) + (quad << 3)) & 31) * 8);
                    ol[g] = __builtin_amdgcn_mfma_f32_16x16x32_fp8_fp8(pf, ONES8, ol[g], 0, 0, 0);
                    for (int nd = 0; nd < 4; nd++)
                        o[g][nd] = __builtin_amdgcn_mfma_f32_16x16x32_fp8_fp8(pf, vv[nd][kh], o[g][nd], 0, 0, 0);
                }
            }
        }
    }

    // l: C rows = q offset quad*4+r, cols identical -> write from l16==0
    if (l16 == 0)
        for (int g = 0; g < 2; g++)
            for (int r = 0; r < 4; r++)
                atomicAdd(&l_tot[(h << 12) + qbase + g * 16 + quad * 4 + r], ol[g][r]);

    for (int g = 0; g < 2; g++)
        for (int nd = 0; nd < 4; nd++)
            for (int r = 0; r < 4; r++) {
                int q = qbase + g * 16 + quad * 4 + r;
                atomicAdd(&vals[hoff + (size_t)q * DK + nd * 16 + l16], o[g][nd][r]);
            }
}

// ----------------- deferred normalize + residual + LayerNorm ---------------
__global__ __launch_bounds__(256) void ln_kernel(
    const float* __restrict__ vals, const float* __restrict__ l_tot,
    const float* __restrict__ x,
    const float* __restrict__ gamma, const float* __restrict__ beta,
    float* __restrict__ out) {
    const int wave = threadIdx.x >> 6, lane = threadIdx.x & 63;
    const int row  = blockIdx.x * 4 + wave;
    const float* v  = vals + (size_t)row * D_MODEL;
    const float* xr = x    + (size_t)row * D_MODEL;

    float t[10];
    float s = 0.f;
    for (int i = 0; i < 10; i++) {
        float linv = 1.0f / l_tot[row * 10 + i];
        t[i] = v[lane + i * 64] * linv + xr[lane + i * 64];
        s += t[i];
    }
    for (int off = 32; off; off >>= 1) s += __shfl_xor(s, off, 64);
    float mean = s * (1.0f / 640.0f);
    float s2 = 0.f;
    for (int i = 0; i < 10; i++) { float d = t[i] - mean; s2 += d * d; }
    for (int off = 32; off; off >>= 1) s2 += __shfl_xor(s2, off, 64);
    float inv = rsqrtf(s2 * (1.0f / 640.0f) + 1e-5f);

    float* orow = out + (size_t)row * D_MODEL;
    for (int i = 0; i < 10; i++) {
        int c = lane + i * 64;
        orow[c] = (t[i] - mean) * inv * gamma[c] + beta[c];
    }
}

// ------------------------------- launcher ----------------------------------
extern "C" void kernel_launch(void* const* d_in, const int* in_sizes, int n_in,
                              void* d_out, int out_size, void* d_ws, size_t ws_size,
                              hipStream_t stream) {
    const float* x     = (const float*)d_in[0];
    const float* Wq    = (const float*)d_in[1];
    const float* Wk    = (const float*)d_in[2];
    const float* Wv    = (const float*)d_in[3];
    const float* gamma = (const float*)d_in[4];
    const float* beta  = (const float*)d_in[5];
    float* out = (float*)d_out;

    char* ws = (char*)d_ws;
    unsigned short* xb  = (unsigned short*)(ws);               // 5,242,880 B
    unsigned short* wqb = (unsigned short*)(ws + 5242880);
    unsigned short* wkb = (unsigned short*)(ws + 6062080);
    unsigned short* wvb = (unsigned short*)(ws + 6881280);
    unsigned char*  Qf8 = (unsigned char*)(ws + 7700480);      // fp8 Q
    unsigned char*  Kp8 = (unsigned char*)(ws + 12943360);     // fp8 K' [h][key][dk-perm]
    unsigned char*  Vp8 = (unsigned char*)(ws + 18186240);     // fp8 V' [h][dk][key-perm]
    unsigned short* Kn  = (unsigned short*)(ws + 23429120);    // aliases vals
    unsigned short* Vn  = (unsigned short*)(ws + 28672000);    //  (exactly)
    float*          vals  = (float*)(ws + 23429120);           // 10,485,760 B
    float*          l_tot = (float*)(ws + 33914880);           //   163,840 B

    cvt_all<<<3800, 256, 0, stream>>>(x, Wq, Wk, Wv, xb, wqb, wkb, wvb,
                                      (f32x4*)l_tot);

    gemm_qkv<<<960, 256, 0, stream>>>(xb, wqb, wkb, wvb, Qf8, Kn, Vn);

    transpose_kv<<<dim3(64, 1, 20), 256, 0, stream>>>(Kn, Kp8, Vn, Vp8);

    attn<<<dim3(320, 3), 256, 0, stream>>>(Qf8, Kp8, Vp8, vals, l_tot);
    ln_kernel<<<1024, 256, 0, stream>>>(vals, l_tot, x, gamma, beta, out);
}

// Round 12
// 147.437 us; speedup vs baseline: 1.0230x; 1.0230x over previous
//
#include <hip/hip_runtime.h>
#if __has_include(<hip/hip_fp8.h>)
#include <hip/hip_fp8.h>
#endif

// ---------------------------------------------------------------------------
// MHABlock: cvt (+l_tot zero, sqrt-softmax-scale folded into Wq AND Wk) ->
// QKV GEMM (bf16, 128x128 tiles, BK=128, global_load_lds, XCD-pinned
// m-tiles; Q-mode writes fp8 directly) -> fused K/V transpose + fp8 convert
// (+vals zero; rows PERMUTED at 8B level for conflict-free b128 attn reads)
// -> split-K(3) fp8 flash attention (R20 loop, HEAD->XCD-PINNED grid) ->
// deferred normalize + LN.
//
// R26: revert R25's gemm tile shrink (150.8 vs R24 147.5 -> tile-shrink
// hurts; BK=128 128^2 banked). New: attn head->XCD pinning. FETCH was
// 21.8MB vs 7.9MB ideal: linear blockIdx round-robins the 32 same-head
// q-blocks over all 8 XCD L2s, so every XCD refetches every head's 512KB
// K'/V' from HBM. HBM latency (~900cy) > S-phase (~500-800cy) -> the
// per-tile vmcnt drain stalls; L2 latency (~200cy) < S-phase -> drain free.
// Remap (bijective, 40 blocks/XCD uniform): c=bx&7, s=bx>>3; s<32: h=c,
// qt=s; s>=32: h=8+(c&1), qt=(s-32)*4+(c>>1). Heads 0-7 one XCD each,
// heads 8-9 split over 4. kparts (y) keep x -> same XCD.
// ---------------------------------------------------------------------------

typedef __bf16 bf16x8 __attribute__((ext_vector_type(8)));
typedef __bf16 bf16x4 __attribute__((ext_vector_type(4)));
typedef float  f32x4  __attribute__((ext_vector_type(4)));
typedef unsigned short u16x4 __attribute__((ext_vector_type(4)));
typedef unsigned int   u32x4 __attribute__((ext_vector_type(4)));
typedef long           lx2   __attribute__((ext_vector_type(2)));
typedef lx2            lx2a  __attribute__((may_alias));
typedef long           la64  __attribute__((may_alias));
typedef unsigned int   ua32  __attribute__((may_alias));

#define N_TOK   4096
#define D_MODEL 640
#define DK      64
#define HSLAB   (N_TOK * DK)
// sqrt(log2(e)/64): folded into BOTH Wq and Wk -> logits arrive base-2 scaled
#define SQS 0.15014030f

#if __has_builtin(__builtin_amdgcn_exp2f)
#define EXP2(x) __builtin_amdgcn_exp2f(x)
#else
#define EXP2(x) exp2f(x)
#endif

__device__ __forceinline__ void stage16(const void* g, void* lds_uniform) {
    __builtin_amdgcn_global_load_lds(
        (const __attribute__((address_space(1))) unsigned int*)g,
        (__attribute__((address_space(3))) unsigned int*)lds_uniform, 16, 0, 0);
}

__device__ __forceinline__ u16x4 cvt4(f32x4 v) {
    return __builtin_bit_cast(u16x4, __builtin_convertvector(v, bf16x4));
}

__device__ __forceinline__ unsigned int pk_fp8(f32x4 v) {
#if __has_builtin(__builtin_amdgcn_cvt_pk_fp8_f32)
    int r = 0;
    r = __builtin_amdgcn_cvt_pk_fp8_f32(v[0], v[1], r, false);
    r = __builtin_amdgcn_cvt_pk_fp8_f32(v[2], v[3], r, true);
    return (unsigned int)r;
#else
    union { unsigned char b[4]; unsigned int u; } x;
    x.b[0] = __hip_fp8_e4m3(v[0]).__x;
    x.b[1] = __hip_fp8_e4m3(v[1]).__x;
    x.b[2] = __hip_fp8_e4m3(v[2]).__x;
    x.b[3] = __hip_fp8_e4m3(v[3]).__x;
    return x.u;
#endif
}

// ---------- fused fp32 -> bf16 (x, Wq*s, Wk*s, Wv) + l_tot zeroing ---------
__global__ __launch_bounds__(256) void cvt_all(const float* __restrict__ x,
                                               const float* __restrict__ w0,
                                               const float* __restrict__ w1,
                                               const float* __restrict__ w2,
                                               unsigned short* __restrict__ xb,
                                               unsigned short* __restrict__ d0,
                                               unsigned short* __restrict__ d1,
                                               unsigned short* __restrict__ d2,
                                               f32x4* __restrict__ ltot4) {
    int i = blockIdx.x * 256 + threadIdx.x;
    if (i >= 962560) { ltot4[i - 962560] = (f32x4){0.f, 0.f, 0.f, 0.f}; return; }
    const float* s; unsigned short* d; int off; float scl = 1.0f;
    if (i < 655360) { s = x; d = xb; off = i; }
    else {
        int j = i - 655360;
        int w = j / 102400; off = j - w * 102400;
        s = (w == 0) ? w0 : (w == 1) ? w1 : w2;
        d = (w == 0) ? d0 : (w == 1) ? d1 : d2;
        if (w < 2) scl = SQS;   // Wq, Wk carry sqrt of softmax scale
    }
    f32x4 v = ((const f32x4*)s)[off];
    v[0] *= scl; v[1] *= scl; v[2] *= scl; v[3] *= scl;
    ((u16x4*)d)[off] = cvt4(v);
}

// ------------------------ QKV NT-GEMM: C = x @ W^T -------------------------
// M=4096, N=640, K=640. 128x128 tile, BK=128 (5 K-steps), 4 waves each 64x64.
// Grid 480 linear, XCD-pinned m-tiles (g = b&31 -> g%8 == XCD id).
// mode 0 (Q): epilogue converts straight to fp8.
__global__ __launch_bounds__(256, 2) void gemm_qkv(
    const unsigned short* __restrict__ xb,
    const unsigned short* __restrict__ wq,
    const unsigned short* __restrict__ wk,
    const unsigned short* __restrict__ wv,
    unsigned char*  __restrict__ Qf8o,
    unsigned short* __restrict__ Ko,
    unsigned short* __restrict__ Vo) {
    const int b = blockIdx.x;
    const int g = b & 31;            // m-tile (XCD-pinned)
    const int r = b >> 5;            // 0..14 = (mode, n-tile)
    const int mode = r / 5;
    const int m0 = g * 128;
    const int n0 = (r % 5) * 128;
    const unsigned short* W = (mode == 0) ? wq : (mode == 1) ? wk : wv;
    unsigned short*       C = (mode == 1) ? Ko : Vo;

    __shared__ unsigned short As[16384];   // 128 rows x 128
    __shared__ unsigned short Bs[16384];

    const int tid  = threadIdx.x;
    const int lane = tid & 63;
    const int wave = tid >> 6;
    const int quad = lane >> 4, l16 = lane & 15;
    const int wm = (wave >> 1) * 64, wn = (wave & 1) * 64;
    const int swz = l16 & 7;

    f32x4 acc[4][4] = {};

    // chunk p = j*256+tid (0..2047): row = p>>4 (16 chunks of 8 bf16/row),
    // source col-chunk = (p&15)^(row&7) (low-3-bit XOR, bijective per row).
    int prow[8], pcol[8], lbase[8];
    for (int j = 0; j < 8; j++) {
        int p = j * 256 + tid;
        prow[j] = p >> 4;
        pcol[j] = ((p & 15) ^ (prow[j] & 7)) * 8;
        lbase[j] = (j * 256 + wave * 64) * 8;
    }

    for (int kt = 0; kt < D_MODEL; kt += 128) {
        __syncthreads();
        for (int j = 0; j < 8; j++) {
            stage16(&xb[(size_t)(m0 + prow[j]) * D_MODEL + kt + pcol[j]], As + lbase[j]);
            stage16(&W [(size_t)(n0 + prow[j]) * D_MODEL + kt + pcol[j]], Bs + lbase[j]);
        }
        __syncthreads();

        for (int s = 0; s < 4; s++) {
            bf16x8 af[4], bfr[4];
            for (int mi = 0; mi < 4; mi++) {
                int row = wm + mi * 16 + l16;
                af[mi] = *(const bf16x8*)&As[row * 128 + ((((s << 2) + quad) ^ swz) * 8)];
            }
            for (int ni = 0; ni < 4; ni++) {
                int row = wn + ni * 16 + l16;
                bfr[ni] = *(const bf16x8*)&Bs[row * 128 + ((((s << 2) + quad) ^ swz) * 8)];
            }
            for (int mi = 0; mi < 4; mi++)
                for (int ni = 0; ni < 4; ni++)
                    acc[mi][ni] = __builtin_amdgcn_mfma_f32_16x16x32_bf16(af[mi], bfr[ni], acc[mi][ni], 0, 0, 0);
        }
    }

    if (mode == 0) {
        for (int mi = 0; mi < 4; mi++)
            for (int ni = 0; ni < 4; ni++) {
                unsigned int p = pk_fp8(acc[mi][ni]);
                for (int r2 = 0; r2 < 4; r2++) {
                    int row = m0 + wm + mi * 16 + quad * 4 + r2;
                    int col = n0 + wn + ni * 16 + l16;
                    Qf8o[(size_t)row * D_MODEL + col] = (unsigned char)(p >> (r2 * 8));
                }
            }
    } else {
        for (int mi = 0; mi < 4; mi++)
            for (int ni = 0; ni < 4; ni++) {
                u16x4 cv = cvt4(acc[mi][ni]);
                for (int r2 = 0; r2 < 4; r2++) {
                    int row = m0 + wm + mi * 16 + quad * 4 + r2;
                    int col = n0 + wn + ni * 16 + l16;
                    C[(size_t)row * D_MODEL + col] = cv[r2];
                }
            }
    }
}

// ------ fused per-head transpose -> fp8 (K',V') + vals zero ----------------
// R20: dst bytes within each 64B group are PERMUTED: original in-group byte
// p lands at p' = ((p&31)>>3)*16 + (p>>5)*8 + (p&7) -> single ds_read_b128
// per operand pair in attn, even bank spread.
__global__ __launch_bounds__(256) void transpose_kv(
    const unsigned short* __restrict__ Kn, unsigned char* __restrict__ Kp8,
    const unsigned short* __restrict__ Vn, unsigned char* __restrict__ Vp8) {
    const int z = blockIdx.z;
    const int t = threadIdx.x;

    __shared__ unsigned short T[64][66];
    const unsigned short* src; unsigned char* dst;
    int R, Cc, r0, c0;
    if (z < 10) { src = Kn; dst = Kp8; R = 64;   Cc = 4096; r0 = 0; c0 = blockIdx.x * 64; }
    else        { src = Vn; dst = Vp8; R = 4096; Cc = 64;   r0 = blockIdx.x * 64; c0 = 0; }
    const size_t hb = (size_t)(z % 10) * HSLAB;
    const int rr = t >> 3, c8 = (t & 7) * 8;
    const int pbase = ((c8 & 31) >> 3) * 16 + (c8 >> 5) * 8;   // 8B-block permute

    for (int hf = 0; hf < 2; hf++) {
        int r = rr + hf * 32;
        bf16x8 v = *(const bf16x8*)&src[hb + (size_t)(r0 + r) * Cc + c0 + c8];
        for (int j = 0; j < 8; j++) T[r][c8 + j] = ((unsigned short*)&v)[j];
    }
    __syncthreads();
    // zero the consumed source tile (Kn+Vn exactly cover the fp32 vals buf)
    const bf16x8 zz = {};
    for (int hf = 0; hf < 2; hf++) {
        int r = rr + hf * 32;
        *(bf16x8*)&((unsigned short*)src)[hb + (size_t)(r0 + r) * Cc + c0 + c8] = zz;
    }
    for (int hf = 0; hf < 2; hf++) {
        int oc = rr + hf * 32;
        f32x4 lo, hi;
        for (int j = 0; j < 4; j++) {
            lo[j] = __builtin_bit_cast(float, (unsigned int)T[c8 + j][oc] << 16);
            hi[j] = __builtin_bit_cast(float, (unsigned int)T[c8 + 4 + j][oc] << 16);
        }
        uint2 ov; ov.x = pk_fp8(lo); ov.y = pk_fp8(hi);
        size_t dcol = (z < 10) ? ((size_t)(c0 + oc) * 64 + pbase)
                               : ((size_t)oc * 4096 + r0 + pbase);
        *(uint2*)&dst[hb + dcol] = ov;
    }
}

// ------------------------------- attention (fp8) ---------------------------
// grid (320, 3): x remapped head->XCD (see header), y = kpart (11/11/10
// tiles of 128 keys). 4 waves x 32 q. 2 barriers/tile, ping-pong K, V under
// S (R14 schedule; R20 conflict-free K/V LDS addressing).
__global__ __launch_bounds__(256, 4) void attn(
    const unsigned char* __restrict__ Qf8,   // [h][q][dk] fp8
    const unsigned char* __restrict__ Kp8,   // [h][key][dk-permuted] fp8
    const unsigned char* __restrict__ Vp8,   // [h][dk][key-permuted] fp8
    float* __restrict__ vals,                // pre-zeroed (transpose_kv)
    float* __restrict__ l_tot) {             // pre-zeroed (cvt_all)
    // head->XCD pinning: XCD = linear_id % 8; give each XCD one head
    // (heads 0-7) or half of heads 8/9. Bijective; 40 x-blocks per XCD.
    const int bx = blockIdx.x;
    const int c  = bx & 7;
    const int s_ = bx >> 3;
    const int h  = (s_ < 32) ? c : 8 + (c & 1);
    const int qt = (s_ < 32) ? s_ : ((s_ - 32) << 2) + (c >> 1);
    const int ntile = (blockIdx.y == 2) ? 10 : 11;
    const int tile0 = blockIdx.y * 11;
    const int lane = threadIdx.x & 63;
    const int wave = threadIdx.x >> 6;
    const int quad = lane >> 4, l16 = lane & 15;
    const size_t hoff = (size_t)h * HSLAB;

    __shared__ unsigned char sm[40960];
    unsigned char* const Kb0 = sm;                      // 8KB, ping
    unsigned char* const Kb1 = sm + 8192;               // 8KB, pong
    unsigned char* const Vt  = sm + 16384;              // 8KB
    unsigned char* const Pw  = sm + 24576 + wave * 4096;// 4KB/wave

    const int qbase = qt * 128 + wave * 32;
    long qd[2][2];
    for (int g = 0; g < 2; g++) {
        const unsigned char* qp = Qf8 + hoff + (size_t)(qbase + g * 16 + l16) * 64 + quad * 8;
        qd[g][0] = *(const la64*)(qp);
        qd[g][1] = *(const la64*)(qp + 32);
    }

    f32x4 o[2][4] = {};
    f32x4 ol[2] = {};
    const long ONES8 = 0x3838383838383838L;   // e4m3 1.0 x8

    // staging chunks (16B each, 2 per thread per buffer): LDS dest linear
    // (chunk c at byte c*16). K source linear; V source inverse-swizzled.
    const int cA = wave * 64 + lane, cB = cA + 256;
    const int vDA = cA >> 3, vSA = ((cA & 7) * 16) ^ ((vDA & 7) << 4);
    const int vDB = cB >> 3, vSB = ((cB & 7) * 16) ^ ((vDB & 7) << 4);

    // fragment-read bases
    const int kfb = l16 * 64 + quad * 16;     // + ni*1024, b128
    const int vrb = l16 * 128;                // + nd*2048, b128
    const int vx  = (l16 & 7) << 4;           // V row XOR

    // prologue: stage K tile 0 into Kb0
    {
        const size_t kb0 = hoff + (size_t)(tile0 << 7) * 64;
        stage16(Kp8 + kb0 + cA * 16, Kb0 + wave * 1024);
        stage16(Kp8 + kb0 + cB * 16, Kb0 + 4096 + wave * 1024);
    }

    for (int t = 0; t < ntile; t++) {
        const int keyb = (tile0 + t) << 7;
        unsigned char* const Kcur = (t & 1) ? Kb1 : Kb0;

        // K[t] drained by previous mid barrier (or here for t=0); Vt/Pw reads
        // of t-1 complete; K[t+1] buffer free.
        __syncthreads();

        if (t + 1 < ntile) {
            const size_t kbn = hoff + (size_t)((tile0 + t + 1) << 7) * 64;
            unsigned char* const Knext = (t & 1) ? Kb0 : Kb1;
            stage16(Kp8 + kbn + cA * 16, Knext + wave * 1024);
            stage16(Kp8 + kbn + cB * 16, Knext + 4096 + wave * 1024);
        }
        stage16(Vp8 + hoff + (size_t)vDA * N_TOK + keyb + vSA, Vt + wave * 1024);
        stage16(Vp8 + hoff + (size_t)vDB * N_TOK + keyb + vSB, Vt + 4096 + wave * 1024);

        // ---- S^T: A = K rows (key), B = Q (pre-scaled); exp2 -> P fp8 ----
        for (int ni = 0; ni < 8; ni++) {
            lx2 kk = *(const lx2a*)(Kcur + ni * 1024 + kfb);
            for (int g = 0; g < 2; g++) {
                f32x4 s = {};
                s = __builtin_amdgcn_mfma_f32_16x16x32_fp8_fp8(kk[0], qd[g][0], s, 0, 0, 0);
                s = __builtin_amdgcn_mfma_f32_16x16x32_fp8_fp8(kk[1], qd[g][1], s, 0, 0, 0);
                f32x4 pv;
                for (int r = 0; r < 4; r++) pv[r] = EXP2(s[r]);
                const int pu = ni * 2 + (quad >> 1);
                *(ua32*)(Pw + pu * 256 +
                         (((g * 16 + l16) + ((pu & 3) << 3)) & 31) * 8 +
                         (quad & 1) * 4) = pk_fp8(pv);
            }
        }

        // Drains vmcnt (V[t] + K[t+1] staged) and lgkmcnt (P visible).
        __syncthreads();

        // ---- O += P * V, l += P * 1 ----
        for (int ksp = 0; ksp < 2; ksp++) {
            lx2 vv[4];
            for (int nd = 0; nd < 4; nd++)
                vv[nd] = *(const lx2a*)(Vt + nd * 2048 + vrb +
                                        ((ksp * 64 + quad * 16) ^ vx));
            for (int kh = 0; kh < 2; kh++) {
                const int ks = ksp * 2 + kh;
                for (int g = 0; g < 2; g++) {
                    // reader pu = ks*4+quad -> pu&3 == quad
                    long pf = *(const la64*)(Pw + (ks * 4 + quad) * 256 +
                                             (((g * 16 + l16) + (quad << 3)) & 31) * 8);
                    ol[g] = __builtin_amdgcn_mfma_f32_16x16x32_fp8_fp8(pf, ONES8, ol[g], 0, 0, 0);
                    for (int nd = 0; nd < 4; nd++)
                        o[g][nd] = __builtin_amdgcn_mfma_f32_16x16x32_fp8_fp8(pf, vv[nd][kh], o[g][nd], 0, 0, 0);
                }
            }
        }
    }

    // l: C rows = q offset quad*4+r, cols identical -> write from l16==0
    if (l16 == 0)
        for (int g = 0; g < 2; g++)
            for (int r = 0; r < 4; r++)
                atomicAdd(&l_tot[(h << 12) + qbase + g * 16 + quad * 4 + r], ol[g][r]);

    for (int g = 0; g < 2; g++)
        for (int nd = 0; nd < 4; nd++)
            for (int r = 0; r < 4; r++) {
                int q = qbase + g * 16 + quad * 4 + r;
                atomicAdd(&vals[hoff + (size_t)q * DK + nd * 16 + l16], o[g][nd][r]);
            }
}

// ----------------- deferred normalize + residual + LayerNorm ---------------
__global__ __launch_bounds__(256) void ln_kernel(
    const float* __restrict__ vals, const float* __restrict__ l_tot,
    const float* __restrict__ x,
    const float* __restrict__ gamma, const float* __restrict__ beta,
    float* __restrict__ out) {
    const int wave = threadIdx.x >> 6, lane = threadIdx.x & 63;
    const int row  = blockIdx.x * 4 + wave;
    const float* v  = vals + (size_t)row * D_MODEL;
    const float* xr = x    + (size_t)row * D_MODEL;

    float t[10];
    float s = 0.f;
    for (int i = 0; i < 10; i++) {
        float linv = 1.0f / l_tot[row * 10 + i];
        t[i] = v[lane + i * 64] * linv + xr[lane + i * 64];
        s += t[i];
    }
    for (int off = 32; off; off >>= 1) s += __shfl_xor(s, off, 64);
    float mean = s * (1.0f / 640.0f);
    float s2 = 0.f;
    for (int i = 0; i < 10; i++) { float d = t[i] - mean; s2 += d * d; }
    for (int off = 32; off; off >>= 1) s2 += __shfl_xor(s2, off, 64);
    float inv = rsqrtf(s2 * (1.0f / 640.0f) + 1e-5f);

    float* orow = out + (size_t)row * D_MODEL;
    for (int i = 0; i < 10; i++) {
        int c = lane + i * 64;
        orow[c] = (t[i] - mean) * inv * gamma[c] + beta[c];
    }
}

// ------------------------------- launcher ----------------------------------
extern "C" void kernel_launch(void* const* d_in, const int* in_sizes, int n_in,
                              void* d_out, int out_size, void* d_ws, size_t ws_size,
                              hipStream_t stream) {
    const float* x     = (const float*)d_in[0];
    const float* Wq    = (const float*)d_in[1];
    const float* Wk    = (const float*)d_in[2];
    const float* Wv    = (const float*)d_in[3];
    const float* gamma = (const float*)d_in[4];
    const float* beta  = (const float*)d_in[5];
    float* out = (float*)d_out;

    char* ws = (char*)d_ws;
    unsigned short* xb  = (unsigned short*)(ws);               // 5,242,880 B
    unsigned short* wqb = (unsigned short*)(ws + 5242880);
    unsigned short* wkb = (unsigned short*)(ws + 6062080);
    unsigned short* wvb = (unsigned short*)(ws + 6881280);
    unsigned char*  Qf8 = (unsigned char*)(ws + 7700480);      // fp8 Q
    unsigned char*  Kp8 = (unsigned char*)(ws + 12943360);     // fp8 K' [h][key][dk-perm]
    unsigned char*  Vp8 = (unsigned char*)(ws + 18186240);     // fp8 V' [h][dk][key-perm]
    unsigned short* Kn  = (unsigned short*)(ws + 23429120);    // aliases vals
    unsigned short* Vn  = (unsigned short*)(ws + 28672000);    //  (exactly)
    float*          vals  = (float*)(ws + 23429120);           // 10,485,760 B
    float*          l_tot = (float*)(ws + 33914880);           //   163,840 B

    cvt_all<<<3800, 256, 0, stream>>>(x, Wq, Wk, Wv, xb, wqb, wkb, wvb,
                                      (f32x4*)l_tot);

    gemm_qkv<<<480, 256, 0, stream>>>(xb, wqb, wkb, wvb, Qf8, Kn, Vn);

    transpose_kv<<<dim3(64, 1, 20), 256, 0, stream>>>(Kn, Kp8, Vn, Vp8);

    attn<<<dim3(320, 3), 256, 0, stream>>>(Qf8, Kp8, Vp8, vals, l_tot);
    ln_kernel<<<1024, 256, 0, stream>>>(vals, l_tot, x, gamma, beta, out);
}